// Round 1
// baseline (1466.452 us; speedup 1.0000x reference)
//
#include <hip/hip_runtime.h>
#include <math.h>

// ---------------------------------------------------------------------------
// CoLT5 MoE layer: router (split-bf16 for exact top-2) + 4 dense experts
// (bf16 MFMA, gated epilogue).  Shapes hard-coded: B=4,L=2048 -> T=8192,
// D=1024, 2D=2048, H=4096, E=4.
// Workspace requirement: ~126 MB.
// ---------------------------------------------------------------------------

typedef short bf16x8 __attribute__((ext_vector_type(8)));
typedef float f32x4 __attribute__((ext_vector_type(4)));

__device__ __forceinline__ unsigned short f2bf(float f) {
  unsigned u = __float_as_uint(f);
  u += 0x7FFFu + ((u >> 16) & 1u);          // round-to-nearest-even
  return (unsigned short)(u >> 16);
}
__device__ __forceinline__ float bf2f(unsigned short s) {
  return __uint_as_float(((unsigned)s) << 16);
}
__device__ __forceinline__ float gelu_f(float x) {
  return 0.5f * x * (1.0f + erff(x * 0.70710678118654752f));
}
__device__ __forceinline__ void gload_lds16(const void* g, void* l) {
  __builtin_amdgcn_global_load_lds(
      (const __attribute__((address_space(1))) void*)g,
      (__attribute__((address_space(3))) void*)l, 16, 0, 0);
}

// ---------------------------------------------------------------------------
// convert x (fp32) -> x_hi (bf16) + x_lo (bf16 residual)
// ---------------------------------------------------------------------------
__global__ __launch_bounds__(256) void convert_split_kernel(
    const float* __restrict__ in, unsigned short* __restrict__ hi,
    unsigned short* __restrict__ lo, int n4) {
  int i = blockIdx.x * blockDim.x + threadIdx.x;
  int stride = gridDim.x * blockDim.x;
  for (; i < n4; i += stride) {
    float4 v = ((const float4*)in)[i];
    float f[4] = {v.x, v.y, v.z, v.w};
#pragma unroll
    for (int u = 0; u < 4; ++u) {
      unsigned short h = f2bf(f[u]);
      hi[i * 4 + u] = h;
      lo[i * 4 + u] = f2bf(f[u] - bf2f(h));
    }
  }
}

// ---------------------------------------------------------------------------
// transpose fp32 [R][C] -> bf16 [C][R] (hi, optional lo residual)
// block (32,8); grid (C/32, R/32)
// ---------------------------------------------------------------------------
__global__ __launch_bounds__(256) void transpose_split_kernel(
    const float* __restrict__ in, unsigned short* __restrict__ hi,
    unsigned short* __restrict__ lo, int R, int C) {
  __shared__ float tile[32][33];
  const int c0 = blockIdx.x * 32, r0 = blockIdx.y * 32;
#pragma unroll
  for (int i = 0; i < 4; ++i) {
    int rr = threadIdx.y + i * 8;
    tile[rr][threadIdx.x] = in[(size_t)(r0 + rr) * C + c0 + threadIdx.x];
  }
  __syncthreads();
#pragma unroll
  for (int i = 0; i < 4; ++i) {
    int cc = threadIdx.y + i * 8;
    float v = tile[threadIdx.x][cc];
    unsigned short h = f2bf(v);
    size_t oidx = (size_t)(c0 + cc) * R + r0 + threadIdx.x;
    hi[oidx] = h;
    if (lo) lo[oidx] = f2bf(v - bf2f(h));
  }
}

// ---------------------------------------------------------------------------
// GEMM: C[M][N] = A[M][K] * Bt[N][K]^T   (both bf16-in-ushort), m97 structure:
// 128x128 tile, BK=32, 4 waves (2x2, 64x64 each), global_load_lds width 16.
// epi: 0 Cf=acc | 1 Cf+=acc | 2 Cf=gelu(Cf+acc+bias) | 3 Cb=bf16(gelu(acc+bias))
//      4 Cf=gate*(acc+bias) | 5 Cf+=gate*(acc+bias)
// ---------------------------------------------------------------------------
__global__ __launch_bounds__(256) void gemm_bt_kernel(
    const unsigned short* __restrict__ A, const unsigned short* __restrict__ Bt,
    int M, int N, int K, int epi, float* __restrict__ Cf,
    unsigned short* __restrict__ Cb, const float* __restrict__ bias,
    const float* __restrict__ gate, int gstride) {
  __shared__ alignas(16) unsigned short As[128 * 32];
  __shared__ alignas(16) unsigned short Bs[128 * 32];
  const int tid = threadIdx.x;
  const int lane = tid & 63;
  const int w = tid >> 6;
  const int wr = w >> 1, wc = w & 1;
  const int brow = blockIdx.y * 128;
  const int bcol = blockIdx.x * 128;

  f32x4 acc[4][4] = {};

  const unsigned short* Ab = A + (size_t)brow * K;
  const unsigned short* Bb = Bt + (size_t)bcol * K;
  char* AsB = (char*)As;
  char* BsB = (char*)Bs;

  const int rA = lane & 15;
  const int kg2 = (lane >> 4) * 16;  // byte offset of this lane's k-group

  const int nk = K >> 5;
  for (int kt = 0; kt < nk; ++kt) {
    const int k0 = kt << 5;
    __syncthreads();  // previous iteration's LDS reads done
#pragma unroll
    for (int i = 0; i < 2; ++i) {
      int c = tid + 256 * i;       // chunk id, 16B each; A tile = 512 chunks
      int row = c >> 2;
      int kp = (c & 3) << 3;
      gload_lds16(Ab + (size_t)row * K + (k0 + kp), AsB + c * 16);
      gload_lds16(Bb + (size_t)row * K + (k0 + kp), BsB + c * 16);
    }
    __syncthreads();  // vmcnt(0) drained by compiler before barrier

    bf16x8 a[4], b[4];
#pragma unroll
    for (int m = 0; m < 4; ++m)
      a[m] = *(const bf16x8*)(AsB + (wr * 64 + m * 16 + rA) * 64 + kg2);
#pragma unroll
    for (int n = 0; n < 4; ++n)
      b[n] = *(const bf16x8*)(BsB + (wc * 64 + n * 16 + rA) * 64 + kg2);
#pragma unroll
    for (int m = 0; m < 4; ++m)
#pragma unroll
      for (int n = 0; n < 4; ++n)
        acc[m][n] =
            __builtin_amdgcn_mfma_f32_16x16x32_bf16(a[m], b[n], acc[m][n], 0, 0, 0);
  }

  // epilogue: C/D layout row=(lane>>4)*4+reg, col=lane&15  [measured m89/m91]
  const int cr = (lane >> 4) * 4;
  const int cc = lane & 15;
#pragma unroll
  for (int m = 0; m < 4; ++m) {
#pragma unroll
    for (int n = 0; n < 4; ++n) {
      const int gc = bcol + wc * 64 + n * 16 + cc;
      const float bv = bias ? bias[gc] : 0.0f;
#pragma unroll
      for (int r = 0; r < 4; ++r) {
        const int gr = brow + wr * 64 + m * 16 + cr + r;
        const size_t idx = (size_t)gr * N + gc;
        const float v = acc[m][n][r];
        if (epi == 0) {
          Cf[idx] = v;
        } else if (epi == 1) {
          Cf[idx] += v;
        } else if (epi == 2) {
          Cf[idx] = gelu_f(Cf[idx] + v + bv);
        } else if (epi == 3) {
          Cb[idx] = f2bf(gelu_f(v + bv));
        } else if (epi == 4) {
          Cf[idx] = gate[(size_t)gr * gstride] * (v + bv);
        } else {
          Cf[idx] += gate[(size_t)gr * gstride] * (v + bv);
        }
      }
    }
  }
}

// ---------------------------------------------------------------------------
// router: logits = rh[T][2048] @ rW2[2048][4] + rb2; softmax; top-2;
// combine[T][4] = prob if selected else 0.   One wave per token.
// ---------------------------------------------------------------------------
__global__ __launch_bounds__(256) void router_kernel(
    const float* __restrict__ rh, const float* __restrict__ rW2,
    const float* __restrict__ rb2, float* __restrict__ combine, int T) {
  const int w = threadIdx.x >> 6, lane = threadIdx.x & 63;
  const int t = blockIdx.x * 4 + w;
  if (t >= T) return;
  const float4* rp = (const float4*)(rh + (size_t)t * 2048);
  const float4* wp = (const float4*)rW2;
  float s0 = 0.f, s1 = 0.f, s2 = 0.f, s3 = 0.f;
#pragma unroll 4
  for (int j = 0; j < 8; ++j) {
    int idx = j * 64 + lane;
    float4 v = rp[idx];
    float xv[4] = {v.x, v.y, v.z, v.w};
#pragma unroll
    for (int u = 0; u < 4; ++u) {
      float4 wv = wp[idx * 4 + u];
      s0 += xv[u] * wv.x;
      s1 += xv[u] * wv.y;
      s2 += xv[u] * wv.z;
      s3 += xv[u] * wv.w;
    }
  }
#pragma unroll
  for (int off = 32; off; off >>= 1) {
    s0 += __shfl_down(s0, off);
    s1 += __shfl_down(s1, off);
    s2 += __shfl_down(s2, off);
    s3 += __shfl_down(s3, off);
  }
  if (lane == 0) {
    float lg[4] = {s0 + rb2[0], s1 + rb2[1], s2 + rb2[2], s3 + rb2[3]};
    float mx = fmaxf(fmaxf(lg[0], lg[1]), fmaxf(lg[2], lg[3]));
    float p[4], sum = 0.f;
#pragma unroll
    for (int e = 0; e < 4; ++e) {
      p[e] = expf(lg[e] - mx);
      sum += p[e];
    }
    float inv = 1.0f / sum;
    int i1 = 0;
#pragma unroll
    for (int e = 1; e < 4; ++e)
      if (lg[e] > lg[i1]) i1 = e;  // strict > : lowest index wins ties (jax)
    int i2 = -1;
#pragma unroll
    for (int e = 0; e < 4; ++e)
      if (e != i1 && (i2 < 0 || lg[e] > lg[i2])) i2 = e;
    float4 cw;
    cw.x = (i1 == 0 || i2 == 0) ? p[0] * inv : 0.f;
    cw.y = (i1 == 1 || i2 == 1) ? p[1] * inv : 0.f;
    cw.z = (i1 == 2 || i2 == 2) ? p[2] * inv : 0.f;
    cw.w = (i1 == 3 || i2 == 3) ? p[3] * inv : 0.f;
    ((float4*)combine)[t] = cw;
  }
}

// ---------------------------------------------------------------------------
extern "C" void kernel_launch(void* const* d_in, const int* in_sizes, int n_in,
                              void* d_out, int out_size, void* d_ws,
                              size_t ws_size, hipStream_t stream) {
  const float* x = (const float*)d_in[0];
  const float* rW1 = (const float*)d_in[1];
  const float* rb1 = (const float*)d_in[2];
  const float* rW2 = (const float*)d_in[3];
  const float* rb2 = (const float*)d_in[4];
  const float* We1 = (const float*)d_in[5];
  const float* be1 = (const float*)d_in[6];
  const float* We2 = (const float*)d_in[7];
  const float* be2 = (const float*)d_in[8];
  float* out = (float*)d_out;

  const int T = 8192, D = 1024, D2 = 2048, H = 4096, E = 4;

  char* ws = (char*)d_ws;
  size_t off = 0;
  auto alloc = [&](size_t bytes) {
    char* p = ws + off;
    off = (off + bytes + 255) & ~(size_t)255;
    return p;
  };
  unsigned short* x_hi = (unsigned short*)alloc((size_t)T * D * 2);
  unsigned short* x_lo = (unsigned short*)alloc((size_t)T * D * 2);
  unsigned short* rW1T_hi = (unsigned short*)alloc((size_t)D2 * D * 2);
  unsigned short* rW1T_lo = (unsigned short*)alloc((size_t)D2 * D * 2);
  float* rh = (float*)alloc((size_t)T * D2 * 4);          // 67 MB
  unsigned short* h = (unsigned short*)rh;                // alias: rh dead after router
  float* combine = (float*)alloc((size_t)T * 4 * 4);
  unsigned short* We1T = (unsigned short*)alloc((size_t)H * D * 2);
  unsigned short* We2T = (unsigned short*)alloc((size_t)D * H * 2);
  (void)ws_size;  // requires ~126 MB

  dim3 tb(32, 8);

  // 1. x -> bf16 hi/lo
  convert_split_kernel<<<2048, 256, 0, stream>>>(x, x_hi, x_lo, T * D / 4);
  // 2. rW1 [D][2D] -> rW1T [2D][D] hi/lo
  transpose_split_kernel<<<dim3(D2 / 32, D / 32), tb, 0, stream>>>(
      rW1, rW1T_hi, rW1T_lo, D, D2);
  // 3. split-bf16 router GEMM1: rh = x@rW1 (fp32-accurate), then bias+gelu
  gemm_bt_kernel<<<dim3(D2 / 128, T / 128), 256, 0, stream>>>(
      x_hi, rW1T_hi, T, D2, D, 0, rh, nullptr, nullptr, nullptr, 0);
  gemm_bt_kernel<<<dim3(D2 / 128, T / 128), 256, 0, stream>>>(
      x_lo, rW1T_hi, T, D2, D, 1, rh, nullptr, nullptr, nullptr, 0);
  gemm_bt_kernel<<<dim3(D2 / 128, T / 128), 256, 0, stream>>>(
      x_hi, rW1T_lo, T, D2, D, 2, rh, nullptr, rb1, nullptr, 0);
  // 4. router head + softmax + top2 -> combine[T][4]
  router_kernel<<<T / 4, 256, 0, stream>>>(rh, rW2, rb2, combine, T);
  // 5. experts (dense over tokens, gated epilogue); h aliases rh (now dead)
  for (int e = 0; e < E; ++e) {
    transpose_split_kernel<<<dim3(H / 32, D / 32), tb, 0, stream>>>(
        We1 + (size_t)e * D * H, We1T, nullptr, D, H);
    gemm_bt_kernel<<<dim3(H / 128, T / 128), 256, 0, stream>>>(
        x_hi, We1T, T, H, D, 3, nullptr, h, be1 + (size_t)e * H, nullptr, 0);
    transpose_split_kernel<<<dim3(D / 32, H / 32), tb, 0, stream>>>(
        We2 + (size_t)e * H * D, We2T, nullptr, H, D);
    gemm_bt_kernel<<<dim3(D / 128, T / 128), 256, 0, stream>>>(
        h, We2T, T, D, H, (e == 0) ? 4 : 5, out, nullptr,
        be2 + (size_t)e * D, combine + e, 4);
  }
}

// Round 2
// 1106.556 us; speedup vs baseline: 1.3252x; 1.3252x over previous
//
#include <hip/hip_runtime.h>
#include <math.h>

// ---------------------------------------------------------------------------
// CoLT5 MoE layer, round 2: top-2 sparse expert dispatch.
//  - router GEMM1: single fused 3-product split-bf16 GEMM (fp32-exact top-2)
//  - router head: logits/softmax/top2 + per-expert token lists (atomic append)
//  - experts: gather-GEMM (indirect A rows via per-lane global_load_lds src)
//             -> gelu -> scatter-GEMM (gated += into out)
// Shapes hard-coded: T=8192, D=1024, D2=2048, H=4096, E=4.  ws ~126 MB.
// ---------------------------------------------------------------------------

typedef short bf16x8 __attribute__((ext_vector_type(8)));
typedef float f32x4 __attribute__((ext_vector_type(4)));

__device__ __forceinline__ unsigned short f2bf(float f) {
  unsigned u = __float_as_uint(f);
  u += 0x7FFFu + ((u >> 16) & 1u);  // round-to-nearest-even
  return (unsigned short)(u >> 16);
}
__device__ __forceinline__ float bf2f(unsigned short s) {
  return __uint_as_float(((unsigned)s) << 16);
}
__device__ __forceinline__ float gelu_f(float x) {
  return 0.5f * x * (1.0f + erff(x * 0.70710678118654752f));
}
__device__ __forceinline__ void gload_lds16(const void* g, void* l) {
  __builtin_amdgcn_global_load_lds(
      (const __attribute__((address_space(1))) void*)g,
      (__attribute__((address_space(3))) void*)l, 16, 0, 0);
}

// ---------------------------------------------------------------------------
// x (fp32) -> x_hi (bf16) + x_lo (bf16 residual)
// ---------------------------------------------------------------------------
__global__ __launch_bounds__(256) void convert_split_kernel(
    const float* __restrict__ in, unsigned short* __restrict__ hi,
    unsigned short* __restrict__ lo, int n4) {
  int i = blockIdx.x * blockDim.x + threadIdx.x;
  int stride = gridDim.x * blockDim.x;
  for (; i < n4; i += stride) {
    float4 v = ((const float4*)in)[i];
    float f[4] = {v.x, v.y, v.z, v.w};
#pragma unroll
    for (int u = 0; u < 4; ++u) {
      unsigned short h = f2bf(f[u]);
      hi[i * 4 + u] = h;
      lo[i * 4 + u] = f2bf(f[u] - bf2f(h));
    }
  }
}

// ---------------------------------------------------------------------------
// transpose fp32 [R][C] -> bf16 [C][R] (hi, optional lo residual)
// block (32,8); grid (C/32, R/32)
// ---------------------------------------------------------------------------
__global__ __launch_bounds__(256) void transpose_split_kernel(
    const float* __restrict__ in, unsigned short* __restrict__ hi,
    unsigned short* __restrict__ lo, int R, int C) {
  __shared__ float tile[32][33];
  const int c0 = blockIdx.x * 32, r0 = blockIdx.y * 32;
#pragma unroll
  for (int i = 0; i < 4; ++i) {
    int rr = threadIdx.y + i * 8;
    tile[rr][threadIdx.x] = in[(size_t)(r0 + rr) * C + c0 + threadIdx.x];
  }
  __syncthreads();
#pragma unroll
  for (int i = 0; i < 4; ++i) {
    int cc = threadIdx.y + i * 8;
    float v = tile[threadIdx.x][cc];
    unsigned short h = f2bf(v);
    size_t oidx = (size_t)(c0 + cc) * R + r0 + threadIdx.x;
    hi[oidx] = h;
    if (lo) lo[oidx] = f2bf(v - bf2f(h));
  }
}

// ---------------------------------------------------------------------------
// Fused 3-product split-bf16 GEMM (router GEMM1):
//   rh = gelu( x_hi*W_hi + x_lo*W_hi + x_hi*W_lo + rb1 )  (fp32 accum)
// 128x128 tile, BK=32, 4 waves.  M=8192 N=2048 K=1024.
// ---------------------------------------------------------------------------
__global__ __launch_bounds__(256) void gemm3_router_kernel(
    const unsigned short* __restrict__ Ahi, const unsigned short* __restrict__ Alo,
    const unsigned short* __restrict__ Bhi, const unsigned short* __restrict__ Blo,
    int N, int K, const float* __restrict__ bias, float* __restrict__ Cf) {
  __shared__ alignas(16) unsigned short Sm[4 * 128 * 32];
  const int tid = threadIdx.x;
  const int lane = tid & 63;
  const int w = tid >> 6;
  const int wr = w >> 1, wc = w & 1;
  const int brow = blockIdx.y * 128;
  const int bcol = blockIdx.x * 128;

  f32x4 acc[4][4] = {};
  char* S = (char*)Sm;
  const unsigned short* srcs[4] = {Ahi + (size_t)brow * K, Alo + (size_t)brow * K,
                                   Bhi + (size_t)bcol * K, Blo + (size_t)bcol * K};
  const int rA = lane & 15;
  const int kg2 = (lane >> 4) * 16;

  const int nk = K >> 5;
  for (int kt = 0; kt < nk; ++kt) {
    const int k0 = kt << 5;
    __syncthreads();
#pragma unroll
    for (int i = 0; i < 8; ++i) {
      int c = tid + 256 * i;
      int tile = c >> 9;
      int cc = c & 511;
      int row = cc >> 2;
      int kp = (cc & 3) << 3;
      gload_lds16(srcs[tile] + (size_t)row * K + (k0 + kp), S + c * 16);
    }
    __syncthreads();

    bf16x8 ah[4], al[4], bh[4], bl[4];
#pragma unroll
    for (int m = 0; m < 4; ++m) {
      int ro = (wr * 64 + m * 16 + rA) * 64 + kg2;
      ah[m] = *(const bf16x8*)(S + ro);
      al[m] = *(const bf16x8*)(S + 8192 + ro);
    }
#pragma unroll
    for (int n = 0; n < 4; ++n) {
      int ro = (wc * 64 + n * 16 + rA) * 64 + kg2;
      bh[n] = *(const bf16x8*)(S + 16384 + ro);
      bl[n] = *(const bf16x8*)(S + 24576 + ro);
    }
#pragma unroll
    for (int m = 0; m < 4; ++m)
#pragma unroll
      for (int n = 0; n < 4; ++n) {
        acc[m][n] = __builtin_amdgcn_mfma_f32_16x16x32_bf16(ah[m], bh[n], acc[m][n], 0, 0, 0);
        acc[m][n] = __builtin_amdgcn_mfma_f32_16x16x32_bf16(al[m], bh[n], acc[m][n], 0, 0, 0);
        acc[m][n] = __builtin_amdgcn_mfma_f32_16x16x32_bf16(ah[m], bl[n], acc[m][n], 0, 0, 0);
      }
  }

  const int cr = (lane >> 4) * 4;
  const int ccx = lane & 15;
#pragma unroll
  for (int m = 0; m < 4; ++m)
#pragma unroll
    for (int n = 0; n < 4; ++n) {
      const int gc = bcol + wc * 64 + n * 16 + ccx;
      const float bv = bias[gc];
#pragma unroll
      for (int r = 0; r < 4; ++r) {
        const int gr = brow + wr * 64 + m * 16 + cr + r;
        Cf[(size_t)gr * N + gc] = gelu_f(acc[m][n][r] + bv);
      }
    }
}

// ---------------------------------------------------------------------------
// router head: logits = rh @ rW2 + rb2; softmax; top-2 -> combine[T][4];
// append token to per-expert lists.  One wave per token.
// ---------------------------------------------------------------------------
__global__ __launch_bounds__(256) void router_kernel(
    const float* __restrict__ rh, const float* __restrict__ rW2,
    const float* __restrict__ rb2, float* __restrict__ combine,
    int* __restrict__ cnt, int* __restrict__ list, int T) {
  const int w = threadIdx.x >> 6, lane = threadIdx.x & 63;
  const int t = blockIdx.x * 4 + w;
  if (t >= T) return;
  const float4* rp = (const float4*)(rh + (size_t)t * 2048);
  const float4* wp = (const float4*)rW2;
  float s0 = 0.f, s1 = 0.f, s2 = 0.f, s3 = 0.f;
#pragma unroll 4
  for (int j = 0; j < 8; ++j) {
    int idx = j * 64 + lane;
    float4 v = rp[idx];
    float xv[4] = {v.x, v.y, v.z, v.w};
#pragma unroll
    for (int u = 0; u < 4; ++u) {
      float4 wv = wp[idx * 4 + u];
      s0 += xv[u] * wv.x;
      s1 += xv[u] * wv.y;
      s2 += xv[u] * wv.z;
      s3 += xv[u] * wv.w;
    }
  }
#pragma unroll
  for (int off = 32; off; off >>= 1) {
    s0 += __shfl_down(s0, off);
    s1 += __shfl_down(s1, off);
    s2 += __shfl_down(s2, off);
    s3 += __shfl_down(s3, off);
  }
  if (lane == 0) {
    float lg[4] = {s0 + rb2[0], s1 + rb2[1], s2 + rb2[2], s3 + rb2[3]};
    float mx = fmaxf(fmaxf(lg[0], lg[1]), fmaxf(lg[2], lg[3]));
    float p[4], sum = 0.f;
#pragma unroll
    for (int e = 0; e < 4; ++e) {
      p[e] = expf(lg[e] - mx);
      sum += p[e];
    }
    float inv = 1.0f / sum;
    int i1 = 0;
#pragma unroll
    for (int e = 1; e < 4; ++e)
      if (lg[e] > lg[i1]) i1 = e;  // strict > : lowest index wins ties (jax)
    int i2 = -1;
#pragma unroll
    for (int e = 0; e < 4; ++e)
      if (e != i1 && (i2 < 0 || lg[e] > lg[i2])) i2 = e;
    float4 cw = {0.f, 0.f, 0.f, 0.f};
    ((float*)&cw)[i1] = p[i1] * inv;
    ((float*)&cw)[i2] = p[i2] * inv;
    ((float4*)combine)[t] = cw;
    int p1 = atomicAdd(&cnt[i1], 1);
    list[i1 * 8192 + p1] = t;
    int p2 = atomicAdd(&cnt[i2], 1);
    list[i2 * 8192 + p2] = t;
  }
}

// ---------------------------------------------------------------------------
// gather-GEMM (expert GEMM-A): rows = list[e] tokens of x_hi; Bt = We1T[e];
// h[packed] = bf16(gelu(acc + be1)).  grid (H/128, 64); early-exit on cnt.
// ---------------------------------------------------------------------------
__global__ __launch_bounds__(256) void gemm_gather_kernel(
    const unsigned short* __restrict__ A, const unsigned short* __restrict__ Bt,
    const int* __restrict__ list, const int* __restrict__ cnt_p, int K,
    const float* __restrict__ bias, unsigned short* __restrict__ Cb, int N) {
  const int cnt = *cnt_p;
  const int rb = blockIdx.y;
  if (rb * 128 >= cnt) return;
  __shared__ alignas(16) unsigned short As[128 * 32];
  __shared__ alignas(16) unsigned short Bs[128 * 32];
  const int tid = threadIdx.x;
  const int lane = tid & 63;
  const int w = tid >> 6;
  const int wr = w >> 1, wc = w & 1;
  const int bcol = blockIdx.x * 128;

  // indirect A-row sources (per-lane global addresses; LDS dest stays linear)
  const int arow = tid >> 2;
  const int kp = (tid & 3) << 3;
  int g0 = rb * 128 + arow, g1 = g0 + 64;
  const int tok0 = (g0 < cnt) ? list[g0] : list[rb * 128];
  const int tok1 = (g1 < cnt) ? list[g1] : list[rb * 128];
  const unsigned short* Asrc0 = A + (size_t)tok0 * K + kp;
  const unsigned short* Asrc1 = A + (size_t)tok1 * K + kp;
  const unsigned short* Bb = Bt + (size_t)bcol * K + (size_t)arow * K + kp;

  f32x4 acc[4][4] = {};
  char* AsB = (char*)As;
  char* BsB = (char*)Bs;
  const int rA = lane & 15;
  const int kg2 = (lane >> 4) * 16;

  const int nk = K >> 5;
  for (int kt = 0; kt < nk; ++kt) {
    const int k0 = kt << 5;
    __syncthreads();
    gload_lds16(Asrc0 + k0, AsB + tid * 16);
    gload_lds16(Asrc1 + k0, AsB + (tid + 256) * 16);
    gload_lds16(Bb + k0, BsB + tid * 16);
    gload_lds16(Bb + (size_t)64 * K + k0, BsB + (tid + 256) * 16);
    __syncthreads();

    bf16x8 a[4], b[4];
#pragma unroll
    for (int m = 0; m < 4; ++m)
      a[m] = *(const bf16x8*)(AsB + (wr * 64 + m * 16 + rA) * 64 + kg2);
#pragma unroll
    for (int n = 0; n < 4; ++n)
      b[n] = *(const bf16x8*)(BsB + (wc * 64 + n * 16 + rA) * 64 + kg2);
#pragma unroll
    for (int m = 0; m < 4; ++m)
#pragma unroll
      for (int n = 0; n < 4; ++n)
        acc[m][n] = __builtin_amdgcn_mfma_f32_16x16x32_bf16(a[m], b[n], acc[m][n], 0, 0, 0);
  }

  const int cr = (lane >> 4) * 4;
  const int ccx = lane & 15;
#pragma unroll
  for (int m = 0; m < 4; ++m)
#pragma unroll
    for (int n = 0; n < 4; ++n) {
      const int gc = bcol + wc * 64 + n * 16 + ccx;
      const float bv = bias[gc];
#pragma unroll
      for (int r = 0; r < 4; ++r) {
        const int gr = rb * 128 + wr * 64 + m * 16 + cr + r;
        Cb[(size_t)gr * N + gc] = f2bf(gelu_f(acc[m][n][r] + bv));
      }
    }
}

// ---------------------------------------------------------------------------
// scatter-GEMM (expert GEMM-B): A = packed h; C scatter:
//   out[tok] += combine[tok][e] * (acc + be2).  grid (D/128, 64); early-exit.
// Safe +=: one thread per (tok,col) per dispatch; experts serialized.
// ---------------------------------------------------------------------------
__global__ __launch_bounds__(256) void gemm_scatter_kernel(
    const unsigned short* __restrict__ A, const unsigned short* __restrict__ Bt,
    const int* __restrict__ list, const int* __restrict__ cnt_p, int K, int e,
    const float* __restrict__ bias, const float* __restrict__ combine,
    float* __restrict__ out, int N) {
  const int cnt = *cnt_p;
  const int rb = blockIdx.y;
  if (rb * 128 >= cnt) return;
  __shared__ alignas(16) unsigned short As[128 * 32];
  __shared__ alignas(16) unsigned short Bs[128 * 32];
  const int tid = threadIdx.x;
  const int lane = tid & 63;
  const int w = tid >> 6;
  const int wr = w >> 1, wc = w & 1;
  const int bcol = blockIdx.x * 128;

  const unsigned short* Ab = A + (size_t)rb * 128 * K;
  const unsigned short* Bb = Bt + (size_t)bcol * K;
  f32x4 acc[4][4] = {};
  char* AsB = (char*)As;
  char* BsB = (char*)Bs;
  const int rA = lane & 15;
  const int kg2 = (lane >> 4) * 16;

  const int nk = K >> 5;
  for (int kt = 0; kt < nk; ++kt) {
    const int k0 = kt << 5;
    __syncthreads();
#pragma unroll
    for (int i = 0; i < 2; ++i) {
      int c = tid + 256 * i;
      int row = c >> 2;
      int kpp = (c & 3) << 3;
      gload_lds16(Ab + (size_t)row * K + (k0 + kpp), AsB + c * 16);
      gload_lds16(Bb + (size_t)row * K + (k0 + kpp), BsB + c * 16);
    }
    __syncthreads();

    bf16x8 a[4], b[4];
#pragma unroll
    for (int m = 0; m < 4; ++m)
      a[m] = *(const bf16x8*)(AsB + (wr * 64 + m * 16 + rA) * 64 + kg2);
#pragma unroll
    for (int n = 0; n < 4; ++n)
      b[n] = *(const bf16x8*)(BsB + (wc * 64 + n * 16 + rA) * 64 + kg2);
#pragma unroll
    for (int m = 0; m < 4; ++m)
#pragma unroll
      for (int n = 0; n < 4; ++n)
        acc[m][n] = __builtin_amdgcn_mfma_f32_16x16x32_bf16(a[m], b[n], acc[m][n], 0, 0, 0);
  }

  const int cr = (lane >> 4) * 4;
  const int ccx = lane & 15;
#pragma unroll
  for (int m = 0; m < 4; ++m)
#pragma unroll
    for (int r = 0; r < 4; ++r) {
      const int gl = rb * 128 + wr * 64 + m * 16 + cr + r;
      if (gl >= cnt) continue;
      const int tok = list[gl];
      const float g = combine[(size_t)tok * 4 + e];
      float* orow = out + (size_t)tok * N;
#pragma unroll
      for (int n = 0; n < 4; ++n) {
        const int gc = bcol + wc * 64 + n * 16 + ccx;
        orow[gc] += g * (acc[m][n][r] + bias[gc]);
      }
    }
}

// ---------------------------------------------------------------------------
extern "C" void kernel_launch(void* const* d_in, const int* in_sizes, int n_in,
                              void* d_out, int out_size, void* d_ws,
                              size_t ws_size, hipStream_t stream) {
  const float* x = (const float*)d_in[0];
  const float* rW1 = (const float*)d_in[1];
  const float* rb1 = (const float*)d_in[2];
  const float* rW2 = (const float*)d_in[3];
  const float* rb2 = (const float*)d_in[4];
  const float* We1 = (const float*)d_in[5];
  const float* be1 = (const float*)d_in[6];
  const float* We2 = (const float*)d_in[7];
  const float* be2 = (const float*)d_in[8];
  float* out = (float*)d_out;

  const int T = 8192, D = 1024, D2 = 2048, H = 4096, E = 4;

  char* ws = (char*)d_ws;
  size_t off = 0;
  auto alloc = [&](size_t bytes) {
    char* p = ws + off;
    off = (off + bytes + 255) & ~(size_t)255;
    return p;
  };
  unsigned short* x_hi = (unsigned short*)alloc((size_t)T * D * 2);
  unsigned short* x_lo = (unsigned short*)alloc((size_t)T * D * 2);
  unsigned short* rW1T_hi = (unsigned short*)alloc((size_t)D2 * D * 2);
  unsigned short* rW1T_lo = (unsigned short*)alloc((size_t)D2 * D * 2);
  float* rh = (float*)alloc((size_t)T * D2 * 4);  // 67 MB; aliased by h below
  unsigned short* h = (unsigned short*)rh;        // packed [8192][4096] bf16
  float* combine = (float*)alloc((size_t)T * 4 * 4);
  int* cnt = (int*)alloc(4 * 4);
  int* list = (int*)alloc((size_t)4 * 8192 * 4);
  unsigned short* We1T = (unsigned short*)alloc((size_t)H * D * 2);
  unsigned short* We2T = (unsigned short*)alloc((size_t)D * H * 2);
  (void)ws_size;  // ~127 MB required

  hipMemsetAsync(cnt, 0, 16, stream);
  hipMemsetAsync(out, 0, (size_t)T * D * 4, stream);

  dim3 tb(32, 8);

  // 1. x -> bf16 hi/lo
  convert_split_kernel<<<2048, 256, 0, stream>>>(x, x_hi, x_lo, T * D / 4);
  // 2. rW1 [D][2D] -> rW1T [2D][D] hi/lo
  transpose_split_kernel<<<dim3(D2 / 32, D / 32), tb, 0, stream>>>(
      rW1, rW1T_hi, rW1T_lo, D, D2);
  // 3. fused split-bf16 router GEMM1 + bias + gelu
  gemm3_router_kernel<<<dim3(D2 / 128, T / 128), 256, 0, stream>>>(
      x_hi, x_lo, rW1T_hi, rW1T_lo, D2, D, rb1, rh);
  // 4. router head + top2 + expert token lists
  router_kernel<<<T / 4, 256, 0, stream>>>(rh, rW2, rb2, combine, cnt, list, T);
  // 5. sparse experts (gather GEMM -> gelu -> scatter GEMM, serialized)
  for (int e = 0; e < E; ++e) {
    transpose_split_kernel<<<dim3(H / 32, D / 32), tb, 0, stream>>>(
        We1 + (size_t)e * D * H, We1T, nullptr, D, H);
    gemm_gather_kernel<<<dim3(H / 128, T / 128), 256, 0, stream>>>(
        x_hi, We1T, list + e * 8192, cnt + e, D, be1 + (size_t)e * H, h, H);
    transpose_split_kernel<<<dim3(D / 32, H / 32), tb, 0, stream>>>(
        We2 + (size_t)e * H * D, We2T, nullptr, H, D);
    gemm_scatter_kernel<<<dim3(D / 128, T / 128), 256, 0, stream>>>(
        h, We2T, list + e * 8192, cnt + e, H, e, be2 + (size_t)e * D, combine,
        out, D);
  }
}

// Round 3
// 939.637 us; speedup vs baseline: 1.5607x; 1.1776x over previous
//
#include <hip/hip_runtime.h>
#include <math.h>

// ---------------------------------------------------------------------------
// CoLT5 MoE layer, round 3: fix router atomic contention (201us -> ~25us).
//  - router GEMM1: fused 3-product split-bf16 GEMM (fp32-exact top-2)
//  - logits kernel (no atomics) + topk kernel (block-aggregated list build,
//    128 global atomics total instead of 16K)
//  - experts: gather-GEMM -> gelu -> scatter-GEMM (gated +=), top-2 sparse
// Shapes hard-coded: T=8192, D=1024, D2=2048, H=4096, E=4.  ws ~127 MB.
// ---------------------------------------------------------------------------

typedef short bf16x8 __attribute__((ext_vector_type(8)));
typedef float f32x4 __attribute__((ext_vector_type(4)));

__device__ __forceinline__ unsigned short f2bf(float f) {
  unsigned u = __float_as_uint(f);
  u += 0x7FFFu + ((u >> 16) & 1u);  // round-to-nearest-even
  return (unsigned short)(u >> 16);
}
__device__ __forceinline__ float bf2f(unsigned short s) {
  return __uint_as_float(((unsigned)s) << 16);
}
__device__ __forceinline__ float gelu_f(float x) {
  return 0.5f * x * (1.0f + erff(x * 0.70710678118654752f));
}
__device__ __forceinline__ void gload_lds16(const void* g, void* l) {
  __builtin_amdgcn_global_load_lds(
      (const __attribute__((address_space(1))) void*)g,
      (__attribute__((address_space(3))) void*)l, 16, 0, 0);
}

// ---------------------------------------------------------------------------
// x (fp32) -> x_hi (bf16) + x_lo (bf16 residual); vectorized 8B stores
// ---------------------------------------------------------------------------
__global__ __launch_bounds__(256) void convert_split_kernel(
    const float* __restrict__ in, unsigned short* __restrict__ hi,
    unsigned short* __restrict__ lo, int n4) {
  int i = blockIdx.x * blockDim.x + threadIdx.x;
  int stride = gridDim.x * blockDim.x;
  for (; i < n4; i += stride) {
    float4 v = ((const float4*)in)[i];
    float f[4] = {v.x, v.y, v.z, v.w};
    ushort4 h4, l4;
    unsigned short* hp = (unsigned short*)&h4;
    unsigned short* lp = (unsigned short*)&l4;
#pragma unroll
    for (int u = 0; u < 4; ++u) {
      unsigned short h = f2bf(f[u]);
      hp[u] = h;
      lp[u] = f2bf(f[u] - bf2f(h));
    }
    ((ushort4*)hi)[i] = h4;
    ((ushort4*)lo)[i] = l4;
  }
}

// ---------------------------------------------------------------------------
// transpose fp32 [R][C] -> bf16 [C][R] (hi, optional lo residual)
// block (32,8); grid (C/32, R/32)
// ---------------------------------------------------------------------------
__global__ __launch_bounds__(256) void transpose_split_kernel(
    const float* __restrict__ in, unsigned short* __restrict__ hi,
    unsigned short* __restrict__ lo, int R, int C) {
  __shared__ float tile[32][33];
  const int c0 = blockIdx.x * 32, r0 = blockIdx.y * 32;
#pragma unroll
  for (int i = 0; i < 4; ++i) {
    int rr = threadIdx.y + i * 8;
    tile[rr][threadIdx.x] = in[(size_t)(r0 + rr) * C + c0 + threadIdx.x];
  }
  __syncthreads();
#pragma unroll
  for (int i = 0; i < 4; ++i) {
    int cc = threadIdx.y + i * 8;
    float v = tile[threadIdx.x][cc];
    unsigned short h = f2bf(v);
    size_t oidx = (size_t)(c0 + cc) * R + r0 + threadIdx.x;
    hi[oidx] = h;
    if (lo) lo[oidx] = f2bf(v - bf2f(h));
  }
}

// ---------------------------------------------------------------------------
// Fused 3-product split-bf16 GEMM (router GEMM1):
//   rh = gelu( x_hi*W_hi + x_lo*W_hi + x_hi*W_lo + rb1 )  (fp32 accum)
// 128x128 tile, BK=32, 4 waves.  M=8192 N=2048 K=1024.
// ---------------------------------------------------------------------------
__global__ __launch_bounds__(256) void gemm3_router_kernel(
    const unsigned short* __restrict__ Ahi, const unsigned short* __restrict__ Alo,
    const unsigned short* __restrict__ Bhi, const unsigned short* __restrict__ Blo,
    int N, int K, const float* __restrict__ bias, float* __restrict__ Cf) {
  __shared__ alignas(16) unsigned short Sm[4 * 128 * 32];
  const int tid = threadIdx.x;
  const int lane = tid & 63;
  const int w = tid >> 6;
  const int wr = w >> 1, wc = w & 1;
  const int brow = blockIdx.y * 128;
  const int bcol = blockIdx.x * 128;

  f32x4 acc[4][4] = {};
  char* S = (char*)Sm;
  const unsigned short* srcs[4] = {Ahi + (size_t)brow * K, Alo + (size_t)brow * K,
                                   Bhi + (size_t)bcol * K, Blo + (size_t)bcol * K};
  const int rA = lane & 15;
  const int kg2 = (lane >> 4) * 16;

  const int nk = K >> 5;
  for (int kt = 0; kt < nk; ++kt) {
    const int k0 = kt << 5;
    __syncthreads();
#pragma unroll
    for (int i = 0; i < 8; ++i) {
      int c = tid + 256 * i;
      int tile = c >> 9;
      int cc = c & 511;
      int row = cc >> 2;
      int kp = (cc & 3) << 3;
      gload_lds16(srcs[tile] + (size_t)row * K + (k0 + kp), S + c * 16);
    }
    __syncthreads();

    bf16x8 ah[4], al[4], bh[4], bl[4];
#pragma unroll
    for (int m = 0; m < 4; ++m) {
      int ro = (wr * 64 + m * 16 + rA) * 64 + kg2;
      ah[m] = *(const bf16x8*)(S + ro);
      al[m] = *(const bf16x8*)(S + 8192 + ro);
    }
#pragma unroll
    for (int n = 0; n < 4; ++n) {
      int ro = (wc * 64 + n * 16 + rA) * 64 + kg2;
      bh[n] = *(const bf16x8*)(S + 16384 + ro);
      bl[n] = *(const bf16x8*)(S + 24576 + ro);
    }
#pragma unroll
    for (int m = 0; m < 4; ++m)
#pragma unroll
      for (int n = 0; n < 4; ++n) {
        acc[m][n] = __builtin_amdgcn_mfma_f32_16x16x32_bf16(ah[m], bh[n], acc[m][n], 0, 0, 0);
        acc[m][n] = __builtin_amdgcn_mfma_f32_16x16x32_bf16(al[m], bh[n], acc[m][n], 0, 0, 0);
        acc[m][n] = __builtin_amdgcn_mfma_f32_16x16x32_bf16(ah[m], bl[n], acc[m][n], 0, 0, 0);
      }
  }

  const int cr = (lane >> 4) * 4;
  const int ccx = lane & 15;
#pragma unroll
  for (int m = 0; m < 4; ++m)
#pragma unroll
    for (int n = 0; n < 4; ++n) {
      const int gc = bcol + wc * 64 + n * 16 + ccx;
      const float bv = bias[gc];
#pragma unroll
      for (int r = 0; r < 4; ++r) {
        const int gr = brow + wr * 64 + m * 16 + cr + r;
        Cf[(size_t)gr * N + gc] = gelu_f(acc[m][n][r] + bv);
      }
    }
}

// ---------------------------------------------------------------------------
// logits = rh[T][2048] @ rW2[2048][4] + rb2.  One wave per token, NO atomics.
// ---------------------------------------------------------------------------
__global__ __launch_bounds__(256) void logits_kernel(
    const float* __restrict__ rh, const float* __restrict__ rW2,
    const float* __restrict__ rb2, float* __restrict__ logits, int T) {
  const int w = threadIdx.x >> 6, lane = threadIdx.x & 63;
  const int t = blockIdx.x * 4 + w;
  if (t >= T) return;
  const float4* rp = (const float4*)(rh + (size_t)t * 2048);
  const float4* wp = (const float4*)rW2;
  float s0 = 0.f, s1 = 0.f, s2 = 0.f, s3 = 0.f;
#pragma unroll 4
  for (int j = 0; j < 8; ++j) {
    int idx = j * 64 + lane;
    float4 v = rp[idx];
    float xv[4] = {v.x, v.y, v.z, v.w};
#pragma unroll
    for (int u = 0; u < 4; ++u) {
      float4 wv = wp[idx * 4 + u];
      s0 += xv[u] * wv.x;
      s1 += xv[u] * wv.y;
      s2 += xv[u] * wv.z;
      s3 += xv[u] * wv.w;
    }
  }
#pragma unroll
  for (int off = 32; off; off >>= 1) {
    s0 += __shfl_down(s0, off);
    s1 += __shfl_down(s1, off);
    s2 += __shfl_down(s2, off);
    s3 += __shfl_down(s3, off);
  }
  if (lane == 0) {
    float4 lg = {s0 + rb2[0], s1 + rb2[1], s2 + rb2[2], s3 + rb2[3]};
    ((float4*)logits)[t] = lg;
  }
}

// ---------------------------------------------------------------------------
// topk: softmax + top-2 -> combine[T][4]; per-expert token lists with
// two-level aggregation: wave ballot -> block LDS -> 1 atomic/expert/block.
// One THREAD per token; grid T/256.
// ---------------------------------------------------------------------------
__global__ __launch_bounds__(256) void topk_kernel(
    const float* __restrict__ logits, float* __restrict__ combine,
    int* __restrict__ cnt, int* __restrict__ list, int T) {
  const int t = blockIdx.x * 256 + threadIdx.x;
  const int w = threadIdx.x >> 6, lane = threadIdx.x & 63;
  __shared__ int wpre[4][4];  // [wave][expert]: prefix within block
  __shared__ int gbase[4];    // global base per expert

  float4 lv = ((const float4*)logits)[t];
  float lg[4] = {lv.x, lv.y, lv.z, lv.w};
  float mx = fmaxf(fmaxf(lg[0], lg[1]), fmaxf(lg[2], lg[3]));
  float p[4], sum = 0.f;
#pragma unroll
  for (int e = 0; e < 4; ++e) {
    p[e] = expf(lg[e] - mx);
    sum += p[e];
  }
  float inv = 1.0f / sum;
  int i1 = 0;
#pragma unroll
  for (int e = 1; e < 4; ++e)
    if (lg[e] > lg[i1]) i1 = e;  // strict > : lowest index wins ties (jax)
  int i2 = -1;
#pragma unroll
  for (int e = 0; e < 4; ++e)
    if (e != i1 && (i2 < 0 || lg[e] > lg[i2])) i2 = e;
  float4 cw = {0.f, 0.f, 0.f, 0.f};
  ((float*)&cw)[i1] = p[i1] * inv;
  ((float*)&cw)[i2] = p[i2] * inv;
  ((float4*)combine)[t] = cw;

  unsigned long long m[4];
#pragma unroll
  for (int e = 0; e < 4; ++e)
    m[e] = __ballot(i1 == e || i2 == e);
  if (lane == 0) {
#pragma unroll
    for (int e = 0; e < 4; ++e) wpre[w][e] = (int)__popcll(m[e]);
  }
  __syncthreads();
  if (threadIdx.x < 4) {
    const int e = threadIdx.x;
    int tot = 0;
#pragma unroll
    for (int ww = 0; ww < 4; ++ww) {
      int c = wpre[ww][e];
      wpre[ww][e] = tot;
      tot += c;
    }
    gbase[e] = atomicAdd(&cnt[e], tot);
  }
  __syncthreads();
  const unsigned long long lt = (1ull << lane) - 1ull;
  int p1 = gbase[i1] + wpre[w][i1] + (int)__popcll(m[i1] & lt);
  list[i1 * 8192 + p1] = t;
  int p2 = gbase[i2] + wpre[w][i2] + (int)__popcll(m[i2] & lt);
  list[i2 * 8192 + p2] = t;
}

// ---------------------------------------------------------------------------
// gather-GEMM (expert GEMM-A): rows = list[e] tokens of x_hi; Bt = We1T[e];
// h[packed] = bf16(gelu(acc + be1)).  grid (H/128, 64); early-exit on cnt.
// ---------------------------------------------------------------------------
__global__ __launch_bounds__(256) void gemm_gather_kernel(
    const unsigned short* __restrict__ A, const unsigned short* __restrict__ Bt,
    const int* __restrict__ list, const int* __restrict__ cnt_p, int K,
    const float* __restrict__ bias, unsigned short* __restrict__ Cb, int N) {
  const int cnt = *cnt_p;
  const int rb = blockIdx.y;
  if (rb * 128 >= cnt) return;
  __shared__ alignas(16) unsigned short As[128 * 32];
  __shared__ alignas(16) unsigned short Bs[128 * 32];
  const int tid = threadIdx.x;
  const int lane = tid & 63;
  const int w = tid >> 6;
  const int wr = w >> 1, wc = w & 1;
  const int bcol = blockIdx.x * 128;

  // indirect A-row sources (per-lane global addresses; LDS dest stays linear)
  const int arow = tid >> 2;
  const int kp = (tid & 3) << 3;
  int g0 = rb * 128 + arow, g1 = g0 + 64;
  const int tok0 = (g0 < cnt) ? list[g0] : list[rb * 128];
  const int tok1 = (g1 < cnt) ? list[g1] : list[rb * 128];
  const unsigned short* Asrc0 = A + (size_t)tok0 * K + kp;
  const unsigned short* Asrc1 = A + (size_t)tok1 * K + kp;
  const unsigned short* Bb = Bt + (size_t)bcol * K + (size_t)arow * K + kp;

  f32x4 acc[4][4] = {};
  char* AsB = (char*)As;
  char* BsB = (char*)Bs;
  const int rA = lane & 15;
  const int kg2 = (lane >> 4) * 16;

  const int nk = K >> 5;
  for (int kt = 0; kt < nk; ++kt) {
    const int k0 = kt << 5;
    __syncthreads();
    gload_lds16(Asrc0 + k0, AsB + tid * 16);
    gload_lds16(Asrc1 + k0, AsB + (tid + 256) * 16);
    gload_lds16(Bb + k0, BsB + tid * 16);
    gload_lds16(Bb + (size_t)64 * K + k0, BsB + (tid + 256) * 16);
    __syncthreads();

    bf16x8 a[4], b[4];
#pragma unroll
    for (int m = 0; m < 4; ++m)
      a[m] = *(const bf16x8*)(AsB + (wr * 64 + m * 16 + rA) * 64 + kg2);
#pragma unroll
    for (int n = 0; n < 4; ++n)
      b[n] = *(const bf16x8*)(BsB + (wc * 64 + n * 16 + rA) * 64 + kg2);
#pragma unroll
    for (int m = 0; m < 4; ++m)
#pragma unroll
      for (int n = 0; n < 4; ++n)
        acc[m][n] = __builtin_amdgcn_mfma_f32_16x16x32_bf16(a[m], b[n], acc[m][n], 0, 0, 0);
  }

  const int cr = (lane >> 4) * 4;
  const int ccx = lane & 15;
#pragma unroll
  for (int m = 0; m < 4; ++m)
#pragma unroll
    for (int n = 0; n < 4; ++n) {
      const int gc = bcol + wc * 64 + n * 16 + ccx;
      const float bv = bias[gc];
#pragma unroll
      for (int r = 0; r < 4; ++r) {
        const int gr = rb * 128 + wr * 64 + m * 16 + cr + r;
        Cb[(size_t)gr * N + gc] = f2bf(gelu_f(acc[m][n][r] + bv));
      }
    }
}

// ---------------------------------------------------------------------------
// scatter-GEMM (expert GEMM-B): A = packed h; C scatter:
//   out[tok] += combine[tok][e] * (acc + be2).  grid (D/128, 64); early-exit.
// Safe +=: one thread per (tok,col) per dispatch; experts serialized.
// ---------------------------------------------------------------------------
__global__ __launch_bounds__(256) void gemm_scatter_kernel(
    const unsigned short* __restrict__ A, const unsigned short* __restrict__ Bt,
    const int* __restrict__ list, const int* __restrict__ cnt_p, int K, int e,
    const float* __restrict__ bias, const float* __restrict__ combine,
    float* __restrict__ out, int N) {
  const int cnt = *cnt_p;
  const int rb = blockIdx.y;
  if (rb * 128 >= cnt) return;
  __shared__ alignas(16) unsigned short As[128 * 32];
  __shared__ alignas(16) unsigned short Bs[128 * 32];
  const int tid = threadIdx.x;
  const int lane = tid & 63;
  const int w = tid >> 6;
  const int wr = w >> 1, wc = w & 1;
  const int bcol = blockIdx.x * 128;

  const unsigned short* Ab = A + (size_t)rb * 128 * K;
  const unsigned short* Bb = Bt + (size_t)bcol * K;
  f32x4 acc[4][4] = {};
  char* AsB = (char*)As;
  char* BsB = (char*)Bs;
  const int rA = lane & 15;
  const int kg2 = (lane >> 4) * 16;

  const int nk = K >> 5;
  for (int kt = 0; kt < nk; ++kt) {
    const int k0 = kt << 5;
    __syncthreads();
#pragma unroll
    for (int i = 0; i < 2; ++i) {
      int c = tid + 256 * i;
      int row = c >> 2;
      int kpp = (c & 3) << 3;
      gload_lds16(Ab + (size_t)row * K + (k0 + kpp), AsB + c * 16);
      gload_lds16(Bb + (size_t)row * K + (k0 + kpp), BsB + c * 16);
    }
    __syncthreads();

    bf16x8 a[4], b[4];
#pragma unroll
    for (int m = 0; m < 4; ++m)
      a[m] = *(const bf16x8*)(AsB + (wr * 64 + m * 16 + rA) * 64 + kg2);
#pragma unroll
    for (int n = 0; n < 4; ++n)
      b[n] = *(const bf16x8*)(BsB + (wc * 64 + n * 16 + rA) * 64 + kg2);
#pragma unroll
    for (int m = 0; m < 4; ++m)
#pragma unroll
      for (int n = 0; n < 4; ++n)
        acc[m][n] = __builtin_amdgcn_mfma_f32_16x16x32_bf16(a[m], b[n], acc[m][n], 0, 0, 0);
  }

  const int cr = (lane >> 4) * 4;
  const int ccx = lane & 15;
#pragma unroll
  for (int m = 0; m < 4; ++m)
#pragma unroll
    for (int r = 0; r < 4; ++r) {
      const int gl = rb * 128 + wr * 64 + m * 16 + cr + r;
      if (gl >= cnt) continue;
      const int tok = list[gl];
      const float g = combine[(size_t)tok * 4 + e];
      float* orow = out + (size_t)tok * N;
#pragma unroll
      for (int n = 0; n < 4; ++n) {
        const int gc = bcol + wc * 64 + n * 16 + ccx;
        orow[gc] += g * (acc[m][n][r] + bias[gc]);
      }
    }
}

// ---------------------------------------------------------------------------
extern "C" void kernel_launch(void* const* d_in, const int* in_sizes, int n_in,
                              void* d_out, int out_size, void* d_ws,
                              size_t ws_size, hipStream_t stream) {
  const float* x = (const float*)d_in[0];
  const float* rW1 = (const float*)d_in[1];
  const float* rb1 = (const float*)d_in[2];
  const float* rW2 = (const float*)d_in[3];
  const float* rb2 = (const float*)d_in[4];
  const float* We1 = (const float*)d_in[5];
  const float* be1 = (const float*)d_in[6];
  const float* We2 = (const float*)d_in[7];
  const float* be2 = (const float*)d_in[8];
  float* out = (float*)d_out;

  const int T = 8192, D = 1024, D2 = 2048, H = 4096, E = 4;

  char* ws = (char*)d_ws;
  size_t off = 0;
  auto alloc = [&](size_t bytes) {
    char* p = ws + off;
    off = (off + bytes + 255) & ~(size_t)255;
    return p;
  };
  unsigned short* x_hi = (unsigned short*)alloc((size_t)T * D * 2);
  unsigned short* x_lo = (unsigned short*)alloc((size_t)T * D * 2);
  unsigned short* rW1T_hi = (unsigned short*)alloc((size_t)D2 * D * 2);
  unsigned short* rW1T_lo = (unsigned short*)alloc((size_t)D2 * D * 2);
  float* rh = (float*)alloc((size_t)T * D2 * 4);  // 67 MB; aliased by h below
  unsigned short* h = (unsigned short*)rh;        // packed [8192][4096] bf16
  float* combine = (float*)alloc((size_t)T * 4 * 4);
  float* logits = (float*)alloc((size_t)T * 4 * 4);
  int* cnt = (int*)alloc(4 * 4);
  int* list = (int*)alloc((size_t)4 * 8192 * 4);
  unsigned short* We1T = (unsigned short*)alloc((size_t)H * D * 2);
  unsigned short* We2T = (unsigned short*)alloc((size_t)D * H * 2);
  (void)ws_size;  // ~127 MB required

  hipMemsetAsync(cnt, 0, 16, stream);
  hipMemsetAsync(out, 0, (size_t)T * D * 4, stream);

  dim3 tb(32, 8);

  // 1. x -> bf16 hi/lo
  convert_split_kernel<<<2048, 256, 0, stream>>>(x, x_hi, x_lo, T * D / 4);
  // 2. rW1 [D][2D] -> rW1T [2D][D] hi/lo
  transpose_split_kernel<<<dim3(D2 / 32, D / 32), tb, 0, stream>>>(
      rW1, rW1T_hi, rW1T_lo, D, D2);
  // 3. fused split-bf16 router GEMM1 + bias + gelu
  gemm3_router_kernel<<<dim3(D2 / 128, T / 128), 256, 0, stream>>>(
      x_hi, x_lo, rW1T_hi, rW1T_lo, D2, D, rb1, rh);
  // 4. router head: logits (no atomics), then top2 + aggregated list build
  logits_kernel<<<T / 4, 256, 0, stream>>>(rh, rW2, rb2, logits, T);
  topk_kernel<<<T / 256, 256, 0, stream>>>(logits, combine, cnt, list, T);
  // 5. sparse experts (gather GEMM -> gelu -> scatter GEMM, serialized)
  for (int e = 0; e < E; ++e) {
    transpose_split_kernel<<<dim3(H / 32, D / 32), tb, 0, stream>>>(
        We1 + (size_t)e * D * H, We1T, nullptr, D, H);
    gemm_gather_kernel<<<dim3(H / 128, T / 128), 256, 0, stream>>>(
        x_hi, We1T, list + e * 8192, cnt + e, D, be1 + (size_t)e * H, h, H);
    transpose_split_kernel<<<dim3(D / 32, H / 32), tb, 0, stream>>>(
        We2 + (size_t)e * H * D, We2T, nullptr, H, D);
    gemm_scatter_kernel<<<dim3(D / 128, T / 128), 256, 0, stream>>>(
        h, We2T, list + e * 8192, cnt + e, H, e, be2 + (size_t)e * D, combine,
        out, D);
  }
}